// Round 2
// baseline (473.190 us; speedup 1.0000x reference)
//
#include <hip/hip_runtime.h>

#define KC 32
#define DD 64
#define NB 65536          // batch
#define LOG2PI 1.8378770664093453f

typedef short short8 __attribute__((ext_vector_type(8)));
typedef float f32x4 __attribute__((ext_vector_type(4)));

__device__ __forceinline__ unsigned short f2bf(float f) {
    unsigned int u = __builtin_bit_cast(unsigned int, f);
    u = (u + 0x7FFFu + ((u >> 16) & 1u)) >> 16;   // RNE
    return (unsigned short)u;
}

__device__ __forceinline__ short8 pack8(float4 f0, float4 f1) {
    short8 r;
    r[0] = (short)f2bf(f0.x); r[1] = (short)f2bf(f0.y);
    r[2] = (short)f2bf(f0.z); r[3] = (short)f2bf(f0.w);
    r[4] = (short)f2bf(f1.x); r[5] = (short)f2bf(f1.y);
    r[6] = (short)f2bf(f1.z); r[7] = (short)f2bf(f1.w);
    return r;
}

// ---------------------------------------------------------------------------
// K1: per-component Cholesky + U=L^-1 fully in registers, lane t = row t of L
// (shfl broadcasts, all indices compile-time -> no LDS latency chains).
// Outputs: W in MFMA-fragment-swizzled bf16 order, v = U*c, cdet, acc=0.
// 32 blocks (one per k) x 64 threads (one wave, no barriers in hot loops).
// ---------------------------------------------------------------------------
__global__ __launch_bounds__(64) void prep_kernel(
    const float* __restrict__ cov, const float* __restrict__ centroid,
    unsigned short* __restrict__ wW, float* __restrict__ wV,
    float* __restrict__ wC, float* __restrict__ wAcc)
{
    __shared__ float Ui[64 * 65];    // U columns (stride 65: bank-spread)
    __shared__ float cl[64];
    const int k = blockIdx.x;
    const int t = threadIdx.x;       // 0..63

    // row t of cov -> registers
    float a[64];
    {
        const float4* cov4 = (const float4*)(cov + (size_t)k * 4096 + (size_t)t * 64);
#pragma unroll
        for (int e = 0; e < 16; ++e) {
            float4 f = cov4[e];
            a[4 * e + 0] = f.x; a[4 * e + 1] = f.y;
            a[4 * e + 2] = f.z; a[4 * e + 3] = f.w;
        }
    }
    cl[t] = centroid[k * 64 + t];
    if (k == 0 && t == 0) wAcc[0] = 0.0f;   // ws re-poisoned each launch

    // ---- Cholesky, right-looking, fully unrolled, register-resident ----
    float ldsum = 0.0f;
#pragma unroll
    for (int j = 0; j < 64; ++j) {
        float pv = __shfl(a[j], j);          // pivot A[j][j]
        float r  = rsqrtf(pv);
        float sq = pv * r;                   // sqrt(pivot) = L[j][j]
        ldsum += logf(sq);                   // same value on all lanes
        a[j] = (t == j) ? sq : a[j] * r;     // L[t][j] (t<j lanes: garbage ok)
        float lj = a[j];
#pragma unroll
        for (int p = j + 1; p < 64; ++p) {
            float cjp = __shfl(a[j], p);     // L[p][j] (p>j: valid lanes)
            a[p] = fmaf(-lj, cjp, a[p]);
        }
    }
    if (t == 0) wC[k] = 64.0f * LOG2PI + 2.0f * ldsum;

    // ---- U = L^-1, lane c=t owns column c, fully unrolled ----
    float uc[64];
#pragma unroll
    for (int i = 0; i < 64; ++i) {
        float s = (i == t) ? 1.0f : 0.0f;
#pragma unroll
        for (int j = 0; j < i; ++j) {
            float Lij = __shfl(a[j], i);     // broadcast L[i][j]
            s = fmaf(-Lij, uc[j], s);
        }
        float Lii = __shfl(a[i], i);
        float ri = 1.0f / Lii;
        uc[i] = s * ri;
    }

    // spill U columns to LDS for v + transpose/pack
#pragma unroll
    for (int i = 0; i < 64; ++i) Ui[i * 65 + t] = uc[i];
    __syncthreads();

    // v_d = sum_e U[d][e]*c[e]  (lane d = t)
    {
        float s = 0.0f;
#pragma unroll
        for (int e = 0; e < 64; ++e) s = fmaf(Ui[t * 65 + e], cl[e], s);
        wV[k * 64 + t] = s;
    }

    // W in MFMA-fragment order: wf[((q4*32 + nt)*2 + s)*64 + lane] is the
    // uint4 (8 bf16) lane `lane` feeds to mfma b-frag for n-tile nt, k-half s.
    {
        const int m  = t & 15;
        const int qd = t >> 4;
        const int q4 = k >> 3;
        uint4* wf = (uint4*)wW;
#pragma unroll
        for (int ntl = 0; ntl < 4; ++ntl) {
            int d = ntl * 16 + m;
            int nt = (k & 7) * 4 + ntl;
#pragma unroll
            for (int s2 = 0; s2 < 2; ++s2) {
                int e0 = s2 * 32 + qd * 8;
                float4 f0, f1;
                f0.x = Ui[d * 65 + e0 + 0]; f0.y = Ui[d * 65 + e0 + 1];
                f0.z = Ui[d * 65 + e0 + 2]; f0.w = Ui[d * 65 + e0 + 3];
                f1.x = Ui[d * 65 + e0 + 4]; f1.y = Ui[d * 65 + e0 + 5];
                f1.z = Ui[d * 65 + e0 + 6]; f1.w = Ui[d * 65 + e0 + 7];
                short8 pk = pack8(f0, f1);
                wf[((q4 * 32 + nt) * 2 + s2) * 64 + t] = __builtin_bit_cast(uint4, pk);
            }
        }
    }
}

// ---------------------------------------------------------------------------
// K2: fused gather + GEMM (Z = X W^T via mfma 16x16x32 bf16) + squared-norm
//     epilogue weighted by resp, block-reduced to one atomicAdd.
// Grid: 1024 = 256 row-blocks (256 b each) x 4 N-quarters (512 n = 8 k's).
// Block: 256 thr = 4 waves, wave handles 64 rows x its whole quarter.
// ---------------------------------------------------------------------------
__global__ __launch_bounds__(256) void main_kernel(
    const float* __restrict__ emb, const float* __restrict__ pi,
    const int* __restrict__ labels, const unsigned short* __restrict__ wW,
    const float* __restrict__ wV, const float* __restrict__ wC,
    float* __restrict__ wAcc)
{
    __shared__ int   lab[256];
    __shared__ float Rg[256 * 12];   // resp tile, stride 12 (aligned + bank-spread)
    __shared__ float vq[512];
    __shared__ float cdet[8];
    __shared__ float red[4];

    const int tid = threadIdx.x;
    const int bid = blockIdx.x;
    const int rb = bid & 255;        // row-block
    const int q4 = bid >> 8;         // N-quarter 0..3
    const int row0 = rb * 256;
    const int n0 = q4 * 512;

    lab[tid] = labels[row0 + tid];
    vq[tid] = wV[n0 + tid];
    vq[256 + tid] = wV[n0 + 256 + tid];
    if (tid < 8) cdet[tid] = wC[q4 * 8 + tid];
    __syncthreads();

    // stage resp tile: rows row0..row0+255, k's q4*8..q4*8+7
    {
        const float4* pi4 = (const float4*)pi;
        for (int it = 0; it < 2; ++it) {
            int id = it * 256 + tid;
            int r = id >> 1, h = id & 1;
            float4 f = pi4[(size_t)lab[r] * 8 + q4 * 2 + h];
            *(float4*)&Rg[r * 12 + h * 4] = f;
        }
    }

    const int w  = tid >> 6;   // wave 0..3
    const int l  = tid & 63;
    const int m  = l & 15;     // A row within tile / B col / C col
    const int qd = l >> 4;     // quad

    // A fragments: 4 row-tiles x 2 k-steps, gathered from embedding, fp32->bf16
    short8 afr[4][2];
    {
        const float4* emb4 = (const float4*)emb;
        for (int rt = 0; rt < 4; ++rt) {
            int lb = lab[w * 64 + rt * 16 + m];
            size_t base = (size_t)lb * 16 + qd * 2;
            for (int s = 0; s < 2; ++s) {
                float4 f0 = emb4[base + s * 8];
                float4 f1 = emb4[base + s * 8 + 1];
                afr[rt][s] = pack8(f0, f1);
            }
        }
    }
    __syncthreads();   // Rg ready

    float qa[4][4] = {};
    float part = 0.0f;
    const uint4* wf = (const uint4*)wW;

    for (int nt = 0; nt < 32; ++nt) {
        int nloc = nt * 16 + m;
        int fb = (q4 * 32 + nt) * 2 * 64;
        uint4 u0 = wf[fb + l];          // coalesced: 64 lanes x 16B = 1KB
        uint4 u1 = wf[fb + 64 + l];
        short8 b0 = __builtin_bit_cast(short8, u0);
        short8 b1 = __builtin_bit_cast(short8, u1);
        float vv = vq[nloc];
#pragma unroll
        for (int rt = 0; rt < 4; ++rt) {
            f32x4 cc = {0.0f, 0.0f, 0.0f, 0.0f};
            cc = __builtin_amdgcn_mfma_f32_16x16x32_bf16(afr[rt][0], b0, cc, 0, 0, 0);
            cc = __builtin_amdgcn_mfma_f32_16x16x32_bf16(afr[rt][1], b1, cc, 0, 0, 0);
#pragma unroll
            for (int r2 = 0; r2 < 4; ++r2) {
                float z = cc[r2] - vv;
                qa[rt][r2] = fmaf(z, z, qa[rt][r2]);
            }
        }
        if ((nt & 3) == 3) {               // k complete (its 4 n-tiles done)
            int kloc = nt >> 2;
            float cd = cdet[kloc] * 0.0625f;   // /16: 16 lanes share each (b,k)
#pragma unroll
            for (int rt = 0; rt < 4; ++rt) {
#pragma unroll
                for (int r2 = 0; r2 < 4; ++r2) {
                    int rowl = w * 64 + rt * 16 + qd * 4 + r2;
                    part = fmaf(Rg[rowl * 12 + kloc], qa[rt][r2] + cd, part);
                    qa[rt][r2] = 0.0f;
                }
            }
        }
    }

    for (int off = 32; off > 0; off >>= 1) part += __shfl_down(part, off);
    if (l == 0) red[w] = part;
    __syncthreads();
    if (tid == 0) atomicAdd(wAcc, red[0] + red[1] + red[2] + red[3]);
}

__global__ void fin_kernel(const float* __restrict__ wAcc, float* __restrict__ out) {
    out[0] = fabsf(0.5f * wAcc[0]);
}

extern "C" void kernel_launch(void* const* d_in, const int* in_sizes, int n_in,
                              void* d_out, int out_size, void* d_ws, size_t ws_size,
                              hipStream_t stream) {
    const float* emb    = (const float*)d_in[0];
    const float* cent   = (const float*)d_in[1];
    const float* cov    = (const float*)d_in[2];
    const float* pi     = (const float*)d_in[3];
    const int*   labels = (const int*)d_in[4];
    float* out = (float*)d_out;

    char* w = (char*)d_ws;
    unsigned short* wW = (unsigned short*)w;              // 2048*64 bf16 = 262144 B
    float* wV  = (float*)(w + 262144);                    // 2048 f32   = 8192 B
    float* wC  = (float*)(w + 270336);                    // 32 f32
    float* wAcc = (float*)(w + 270464);                   // 1 f32

    prep_kernel<<<32, 64, 0, stream>>>(cov, cent, wW, wV, wC, wAcc);
    main_kernel<<<1024, 256, 0, stream>>>(emb, pi, labels, wW, wV, wC, wAcc);
    fin_kernel<<<1, 1, 0, stream>>>(wAcc, out);
}

// Round 3
// 346.944 us; speedup vs baseline: 1.3639x; 1.3639x over previous
//
#include <hip/hip_runtime.h>

#define LOG2PI 1.8378770664093453f
#define LN2    0.6931471805599453f

typedef short short8 __attribute__((ext_vector_type(8)));
typedef float f32x4 __attribute__((ext_vector_type(4)));

__device__ __forceinline__ unsigned short f2bf(float f) {
    unsigned int u = __builtin_bit_cast(unsigned int, f);
    u = (u + 0x7FFFu + ((u >> 16) & 1u)) >> 16;   // RNE
    return (unsigned short)u;
}
__device__ __forceinline__ float bf2f(unsigned short h) {
    unsigned int u = ((unsigned int)h) << 16;
    return __builtin_bit_cast(float, u);
}
__device__ __forceinline__ short8 pack8(float4 f0, float4 f1) {
    short8 r;
    r[0] = (short)f2bf(f0.x); r[1] = (short)f2bf(f0.y);
    r[2] = (short)f2bf(f0.z); r[3] = (short)f2bf(f0.w);
    r[4] = (short)f2bf(f1.x); r[5] = (short)f2bf(f1.y);
    r[6] = (short)f2bf(f1.z); r[7] = (short)f2bf(f1.w);
    return r;
}
__device__ __forceinline__ float rdlane(float v, int lane) {
    return __builtin_bit_cast(float, __builtin_amdgcn_readlane(__builtin_bit_cast(int, v), lane));
}

// ---------------------------------------------------------------------------
// K1: Gauss-Jordan in-place inverse of each cov_k (SPD, no pivoting needed),
// lane t owns COLUMN t in registers a[0..63]. Only compile-time register
// indices (inner i-loop unrolled); pivot row/col accessed via readlane +
// cndmask selects. Pivot product -> logdet. One serial phase (not two).
// Outputs: M=cov^-1 as MFMA B-fragments (bf16), v2 = 2*M*c, cdet = D*log2pi
// + logdet + c^T M c, acc = 0.   32 blocks x 64 threads.
// ---------------------------------------------------------------------------
__global__ __launch_bounds__(64) void prep_kernel(
    const float* __restrict__ cov, const float* __restrict__ centroid,
    unsigned short* __restrict__ wW, float* __restrict__ wV2,
    float* __restrict__ wC, float* __restrict__ wAcc)
{
    __shared__ float Mi[64 * 65];
    const int k = blockIdx.x;
    const int t = threadIdx.x;       // 0..63 = owned column

    float a[64];                     // a[i] = A[i][t]
#pragma unroll
    for (int i = 0; i < 64; ++i)
        a[i] = cov[(size_t)k * 4096 + i * 64 + t];

    if (k == 0 && t == 0) wAcc[0] = 0.0f;   // ws re-poisoned each launch

    float rowj = a[0];               // A[j][t] for current step (maintained)
    float ld2 = 0.0f;                // sum log2(pivot)

    for (int j = 0; j < 64; ++j) {
        float pivot = rdlane(rowj, j);
        ld2 += __log2f(pivot);
        float pinv = 1.0f / pivot;
        float rjs = rowj * pinv;               // scaled pivot row
        bool cm = (t == j);                    // column-j mask (per-lane)
        float rowval = cm ? pinv : rjs;        // new row-j values
        float rnew = 0.0f;
#pragma unroll
        for (int i = 0; i < 64; ++i) {
            float cji = rdlane(a[i], j);       // A[i][j] (uniform)
            float fi = cji * pinv;
            float upd = fmaf(-cji, rjs, a[i]); // generic elimination
            upd = cm ? -fi : upd;              // column j -> -A[i][j]/p
            upd = (i == j) ? rowval : upd;     // row j -> row/p (diag 1/p)
            rnew = (i == j + 1) ? upd : rnew;  // capture next pivot row
            a[i] = upd;
        }
        rowj = rnew;
    }
    // a[i] = M[i][t] = inv(cov) column t

#pragma unroll
    for (int i = 0; i < 64; ++i) Mi[i * 65 + t] = a[i];
    __syncthreads();

    // y = (M c)_t ; v2 = 2y ; cMc = sum c_d y_d
    float cme = centroid[k * 64 + t];
    float y = 0.0f;
#pragma unroll
    for (int e = 0; e < 64; ++e)
        y = fmaf(Mi[t * 65 + e], rdlane(cme, e), y);
    wV2[k * 64 + t] = 2.0f * y;
    float cy = cme * y;
#pragma unroll
    for (int off = 32; off > 0; off >>= 1) cy += __shfl_down(cy, off);
    if (t == 0) wC[k] = 64.0f * LOG2PI + ld2 * LN2 + cy;

    // Pack M rows as MFMA B-fragments: frag for n-tile gnt=k*4+ntl, half s2,
    // lane l holds M[d = ntl*16 + (l&15)][e0 .. e0+7], e0 = s2*32 + (l>>4)*8.
    {
        const int m = t & 15, qd = t >> 4;
        uint4* wf = (uint4*)wW;
#pragma unroll
        for (int ntl = 0; ntl < 4; ++ntl) {
            int d = ntl * 16 + m;
#pragma unroll
            for (int s2 = 0; s2 < 2; ++s2) {
                int e0 = s2 * 32 + qd * 8;
                float4 f0, f1;
                f0.x = Mi[d * 65 + e0 + 0]; f0.y = Mi[d * 65 + e0 + 1];
                f0.z = Mi[d * 65 + e0 + 2]; f0.w = Mi[d * 65 + e0 + 3];
                f1.x = Mi[d * 65 + e0 + 4]; f1.y = Mi[d * 65 + e0 + 5];
                f1.z = Mi[d * 65 + e0 + 6]; f1.w = Mi[d * 65 + e0 + 7];
                short8 pk = pack8(f0, f1);
                wf[((k * 4 + ntl) * 2 + s2) * 64 + t] = __builtin_bit_cast(uint4, pk);
            }
        }
    }
}

// ---------------------------------------------------------------------------
// K2: fused gather + GEMM Z = X M^T (mfma 16x16x32 bf16) + epilogue
//     quad = sum_d x_d (z_d - v2_d) + cMc, weighted by resp, one atomic.
// Grid: 512 blocks x 256 thr; block = 128 rows x full N=2048; wave = 8 k's.
// emb/pi rows fetched exactly once chip-wide.
// ---------------------------------------------------------------------------
__global__ __launch_bounds__(256) void main_kernel(
    const float* __restrict__ emb, const float* __restrict__ pi,
    const int* __restrict__ labels, const unsigned short* __restrict__ wW,
    const float* __restrict__ wV2, const float* __restrict__ wC,
    float* __restrict__ wAcc)
{
    __shared__ int lab[128];
    __shared__ unsigned short Xs[128 * 72];   // bf16 x-tile, stride 72 (16B align + bank-spread)
    __shared__ float Rg[128 * 36];            // resp tile, stride 36
    __shared__ float vq[2048];
    __shared__ float cdet[32];
    __shared__ float red[4];

    const int tid = threadIdx.x;
    const int row0 = blockIdx.x * 128;

    if (tid < 128) lab[tid] = labels[row0 + tid];
    if (tid < 32) cdet[tid] = wC[tid];
    {
        const float4* v4 = (const float4*)wV2;
        *(float4*)&vq[tid * 8]     = v4[tid * 2];
        *(float4*)&vq[tid * 8 + 4] = v4[tid * 2 + 1];
    }
    __syncthreads();   // lab ready

    // stage X tile (bf16) — each thread: half a row (32 floats)
    {
        int r = tid >> 1, h = tid & 1;
        const float4* e4 = (const float4*)(emb + (size_t)lab[r] * 64 + h * 32);
#pragma unroll
        for (int q = 0; q < 4; ++q) {
            float4 f0 = e4[q * 2], f1 = e4[q * 2 + 1];
            short8 pk = pack8(f0, f1);
            *(short8*)&Xs[r * 72 + h * 32 + q * 8] = pk;
        }
    }
    // stage resp tile (all 32 k's per row)
    {
        const float4* pi4 = (const float4*)pi;
#pragma unroll
        for (int it = 0; it < 4; ++it) {
            int id = it * 256 + tid;
            int r = id >> 3, c = id & 7;
            float4 f = pi4[(size_t)lab[r] * 8 + c];
            *(float4*)&Rg[r * 36 + c * 4] = f;
        }
    }
    __syncthreads();

    const int w = tid >> 6, l = tid & 63;
    const int m = l & 15, qd = l >> 4;

    // A fragments: 8 row-tiles x 2 k-halves from LDS (16B reads)
    short8 afr[8][2];
#pragma unroll
    for (int rt = 0; rt < 8; ++rt) {
        int row = rt * 16 + m;
#pragma unroll
        for (int s = 0; s < 2; ++s)
            afr[rt][s] = *(const short8*)&Xs[row * 72 + s * 32 + qd * 8];
    }

    float qa[8][4] = {};
    float part = 0.0f;
    const uint4* wf4 = (const uint4*)wW;

    for (int nt = 0; nt < 32; ++nt) {
        int gnt = w * 32 + nt;
        uint4 u0 = wf4[(gnt * 2 + 0) * 64 + l];   // coalesced 1KB/instr
        uint4 u1 = wf4[(gnt * 2 + 1) * 64 + l];
        short8 b0 = __builtin_bit_cast(short8, u0);
        short8 b1 = __builtin_bit_cast(short8, u1);
        float vv = vq[gnt * 16 + m];
        int dcol = (nt & 3) * 16 + m;             // column within the k's D=64
#pragma unroll
        for (int rt = 0; rt < 8; ++rt) {
            f32x4 cc = {0.0f, 0.0f, 0.0f, 0.0f};
            cc = __builtin_amdgcn_mfma_f32_16x16x32_bf16(afr[rt][0], b0, cc, 0, 0, 0);
            cc = __builtin_amdgcn_mfma_f32_16x16x32_bf16(afr[rt][1], b1, cc, 0, 0, 0);
#pragma unroll
            for (int r2 = 0; r2 < 4; ++r2) {
                int rowl = rt * 16 + qd * 4 + r2;
                float xv = bf2f(Xs[rowl * 72 + dcol]);
                qa[rt][r2] = fmaf(xv, cc[r2] - vv, qa[rt][r2]);
            }
        }
        if ((nt & 3) == 3) {                      // k complete
            int kk = w * 8 + (nt >> 2);
            float cd = cdet[kk] * 0.0625f;        // 16 lanes share each (b,k)
#pragma unroll
            for (int rt = 0; rt < 8; ++rt) {
#pragma unroll
                for (int r2 = 0; r2 < 4; ++r2) {
                    int rowl = rt * 16 + qd * 4 + r2;
                    part = fmaf(Rg[rowl * 36 + kk], qa[rt][r2] + cd, part);
                    qa[rt][r2] = 0.0f;
                }
            }
        }
    }

    for (int off = 32; off > 0; off >>= 1) part += __shfl_down(part, off);
    if (l == 0) red[w] = part;
    __syncthreads();
    if (tid == 0) atomicAdd(wAcc, red[0] + red[1] + red[2] + red[3]);
}

__global__ void fin_kernel(const float* __restrict__ wAcc, float* __restrict__ out) {
    out[0] = fabsf(0.5f * wAcc[0]);
}

extern "C" void kernel_launch(void* const* d_in, const int* in_sizes, int n_in,
                              void* d_out, int out_size, void* d_ws, size_t ws_size,
                              hipStream_t stream) {
    const float* emb    = (const float*)d_in[0];
    const float* cent   = (const float*)d_in[1];
    const float* cov    = (const float*)d_in[2];
    const float* pi     = (const float*)d_in[3];
    const int*   labels = (const int*)d_in[4];
    float* out = (float*)d_out;

    char* w = (char*)d_ws;
    unsigned short* wW = (unsigned short*)w;              // 2048*64 bf16 = 262144 B
    float* wV2 = (float*)(w + 262144);                    // 2048 f32
    float* wC  = (float*)(w + 270336);                    // 32 f32
    float* wAcc = (float*)(w + 270464);                   // 1 f32

    prep_kernel<<<32, 64, 0, stream>>>(cov, cent, wW, wV2, wC, wAcc);
    main_kernel<<<512, 256, 0, stream>>>(emb, pi, labels, wW, wV2, wC, wAcc);
    fin_kernel<<<1, 1, 0, stream>>>(wAcc, out);
}